// Round 5
// baseline (2737.178 us; speedup 1.0000x reference)
//
#include <hip/hip_runtime.h>

typedef unsigned short u16;
typedef unsigned int   u32;
typedef unsigned long long u64;
typedef __attribute__((ext_vector_type(8))) short short8;   // 8 x bf16 (4 VGPR)
typedef __attribute__((ext_vector_type(4))) float f32x4;
typedef __attribute__((ext_vector_type(4))) u32   u32x4;

#define NB   64      // batch
#define TS   512     // timesteps
#define HD   512     // hidden
#define RG   4       // row-groups (16 batch rows each)
#define CG   32      // col-groups (16 h-cols each)
#define NBLK (RG*CG) // 128 persistent blocks
#define LP   520     // ldsH pitch in u16 (1040 B)

__device__ __forceinline__ u16 f2bf(float x) {
    union { float f; u32 i; } v; v.f = x;
    u32 r = (v.i + 0x7fffu + ((v.i >> 16) & 1u)) >> 16;
    return (u16)r;
}
__device__ __forceinline__ u32 pack2bf(float a, float b) {
    return (u32)f2bf(a) | ((u32)f2bf(b) << 16);
}
__device__ __forceinline__ float sigmf(float x) { return 1.0f / (1.0f + __expf(-x)); }
__device__ __forceinline__ float tanhf_fast(float x) { return 1.0f - 2.0f / (__expf(2.0f * x) + 1.0f); }

// ---- x: f32 -> bf16, elementwise (one-time) -------------------------------
__global__ void cvt_x_k(const float* __restrict__ in, u16* __restrict__ out, int n) {
    int i = (blockIdx.x * blockDim.x + threadIdx.x) * 8;
    const int stride = gridDim.x * blockDim.x * 8;
    for (; i < n; i += stride) {
        const f32x4 a = *(const f32x4*)(in + i);
        const f32x4 b = *(const f32x4*)(in + i + 4);
        u32 q[4];
        q[0] = pack2bf(a[0], a[1]);
        q[1] = pack2bf(a[2], a[3]);
        q[2] = pack2bf(b[0], b[1]);
        q[3] = pack2bf(b[2], b[3]);
        *(f32x4*)(out + i) = *(f32x4*)q;   // 16B store of 8 bf16
    }
}

// ---- transpose + f32->bf16 convert: in (R x C) f32 -> out (C x R) bf16 ----
__global__ void transpose_cvt_k(const float* __restrict__ in, u16* __restrict__ out,
                                int R, int C) {
    __shared__ float tile[32][33];
    const int c0 = blockIdx.x * 32;
    const int r0 = blockIdx.y * 32;
    const int tx = threadIdx.x & 31;
    const int ty = threadIdx.x >> 5;    // 0..7
#pragma unroll
    for (int i = 0; i < 32; i += 8)
        tile[ty + i][tx] = in[(size_t)(r0 + ty + i) * C + c0 + tx];
    __syncthreads();
#pragma unroll
    for (int i = 0; i < 32; i += 8)
        out[(size_t)(c0 + ty + i) * R + r0 + tx] = f2bf(tile[tx][ty + i]);
}

// ---- persistent fused LSTM ------------------------------------------------
// block (r, cg): batch rows [16r,16r+16), h-cols [16cg,16cg+16)
// wave wv = gate; its 16 gate-cols = wv*512 + cg*16 + [0,16)
// h transport: TAG-IN-DATA. hbuf ring[4][64][512] u32 = (tag16<<16)|bf16(h),
// tag = step+1 (1..512; never 0xAAAA poison). Consumers poll the data words
// directly with relaxed AGENT atomics (LLC-coherent) -- no flags, no fences.
// Ring depth 4 is safe: producer at t+4 implies whole chain finished t+3,
// hence finished reading slot-t data (read during step t+1).
__global__ __launch_bounds__(256, 1) void lstm_fused(
    const u16*   __restrict__ xbg,  // (64,512,512) bf16
    const u16*   __restrict__ WtX,  // (2048,512) bf16 = W_xh^T
    const u16*   __restrict__ WtH,  // (2048,512) bf16 = W_hh^T
    const float* __restrict__ bxh,  // (2048) f32
    const float* __restrict__ bhh,  // (2048) f32
    u32*   __restrict__ hbuf,       // ring: (4, 64, 512) u32 tagged bf16
    float* __restrict__ y)          // (64,512,512) f32
{
    const int bid  = blockIdx.x;
    const int r    = bid & 3;
    const int cg   = bid >> 2;
    const int tid  = threadIdx.x;
    const int lane = tid & 63;
    const int wv   = tid >> 6;          // gate index 0..3
    const int m15  = lane & 15;
    const int kq   = lane >> 4;         // quad 0..3
    const int n0   = r * 16;
    const int gcol0 = wv * 512 + cg * 16;

    __shared__ u16   ldsH[16 * LP];     // 16.6 KB staged h tile (bf16)
    __shared__ float gbuf[4][16][17];

    // --- preload W fragments (B-operand: n = lane&15, k = kq*8 + j) ---
    short8 wx[16], wh[16];
    {
        const u16* px = WtX + (size_t)(gcol0 + m15) * 512 + kq * 8;
        const u16* ph = WtH + (size_t)(gcol0 + m15) * 512 + kq * 8;
#pragma unroll
        for (int kc = 0; kc < 16; ++kc) {
            wx[kc] = *(const short8*)(px + kc * 32);
            wh[kc] = *(const short8*)(ph + kc * 32);
        }
    }
    const float bsum = bxh[gcol0 + m15] + bhh[gcol0 + m15];

    // elementwise ownership: thread -> (erow, ecol) of block's 16x16 h tile
    const int erow = tid >> 4;
    const int ecol = tid & 15;
    const int en   = n0 + erow;
    const int hcol = cg * 16 + ecol;
    float cst = 0.0f;

    // h consume assignment: wave wv polls rows [4wv,4wv+4); lane covers
    // row 4wv+(lane>>4), u32 cols (lane&15)*32 .. +32  (128 B = 16 u64)
    const int lrow = 4 * wv + (lane >> 4);
    const int c0   = (lane & 15) * 32;

    // ---- seed x fragments for t=0 (A-frag: row=m15, k=kq*8+kc*32+j)
    short8 xb[16];
    {
        const u16* xg = xbg + ((size_t)(n0 + m15) * TS + 0) * HD + kq * 8;
#pragma unroll
        for (int kc = 0; kc < 16; ++kc)
            xb[kc] = *(const short8*)(xg + kc * 32);
    }

    for (int t = 0; t < TS; ++t) {
        // ---- x-part MFMA first (retires in background while we poll)
        f32x4 a0 = {0.f,0.f,0.f,0.f}, a1 = {0.f,0.f,0.f,0.f};
        f32x4 a2 = {0.f,0.f,0.f,0.f}, a3 = {0.f,0.f,0.f,0.f};
#pragma unroll
        for (int kc = 0; kc < 4; ++kc) {
            a0 = __builtin_amdgcn_mfma_f32_16x16x32_bf16(xb[4*kc + 0], wx[4*kc + 0], a0, 0, 0, 0);
            a1 = __builtin_amdgcn_mfma_f32_16x16x32_bf16(xb[4*kc + 1], wx[4*kc + 1], a1, 0, 0, 0);
            a2 = __builtin_amdgcn_mfma_f32_16x16x32_bf16(xb[4*kc + 2], wx[4*kc + 2], a2, 0, 0, 0);
            a3 = __builtin_amdgcn_mfma_f32_16x16x32_bf16(xb[4*kc + 3], wx[4*kc + 3], a3, 0, 0, 0);
        }

        if (t > 0) {
            // ---- poll h_{t-1} quarter directly (tag == t in upper halves)
            const u32 tagexp = (u32)t;
            const u64 pat  = ((u64)tagexp << 48) | ((u64)tagexp << 16);
            const u64* src = (const u64*)(hbuf + (size_t)((t - 1) & 3) * (NB * HD)
                                        + (size_t)(n0 + lrow) * HD + c0);
            u64 hq[16];
            bool ok;
            do {
#pragma unroll
                for (int i = 0; i < 16; ++i)
                    hq[i] = __hip_atomic_load(src + i, __ATOMIC_RELAXED,
                                              __HIP_MEMORY_SCOPE_AGENT);
                ok = true;
#pragma unroll
                for (int i = 0; i < 16; ++i)
                    ok = ok && ((hq[i] & 0xFFFF0000FFFF0000ULL) == pat);
            } while (!__all(ok));

            // ---- strip tags, pack pairs -> 16 u32 (32 bf16), share via LDS
            u32 pk[16];
#pragma unroll
            for (int i = 0; i < 16; ++i) {
                const u32 lo = (u32)hq[i];
                const u32 hi = (u32)(hq[i] >> 32);
                pk[i] = (lo & 0xFFFFu) | (hi << 16);
            }
            u32* ldst = (u32*)(ldsH + lrow * LP + (lane & 15) * 32);
            *(u32x4*)(ldst)      = *(u32x4*)(pk);
            *(u32x4*)(ldst + 4)  = *(u32x4*)(pk + 4);
            *(u32x4*)(ldst + 8)  = *(u32x4*)(pk + 8);
            *(u32x4*)(ldst + 12) = *(u32x4*)(pk + 12);
            __syncthreads();                                   // B1

            // ---- h-part MFMA from LDS A-frags
            const u16* lh = ldsH + m15 * LP + kq * 8;
#pragma unroll
            for (int kc = 0; kc < 4; ++kc) {
                short8 h0 = *(const short8*)(lh + (4*kc + 0) * 32);
                short8 h1 = *(const short8*)(lh + (4*kc + 1) * 32);
                short8 h2 = *(const short8*)(lh + (4*kc + 2) * 32);
                short8 h3 = *(const short8*)(lh + (4*kc + 3) * 32);
                a0 = __builtin_amdgcn_mfma_f32_16x16x32_bf16(h0, wh[4*kc + 0], a0, 0, 0, 0);
                a1 = __builtin_amdgcn_mfma_f32_16x16x32_bf16(h1, wh[4*kc + 1], a1, 0, 0, 0);
                a2 = __builtin_amdgcn_mfma_f32_16x16x32_bf16(h2, wh[4*kc + 2], a2, 0, 0, 0);
                a3 = __builtin_amdgcn_mfma_f32_16x16x32_bf16(h3, wh[4*kc + 3], a3, 0, 0, 0);
            }
        }

        // ---- merge gates into LDS (C/D layout: col = lane&15, row = kq*4+reg)
        {
            f32x4 g4 = a0 + a1 + a2 + a3;
#pragma unroll
            for (int j = 0; j < 4; ++j)
                gbuf[wv][kq * 4 + j][m15] = g4[j] + bsum;
        }
        __syncthreads();                                       // B2

        // ---- elementwise LSTM cell; publish tagged h word immediately
        {
            const float gi = gbuf[0][erow][ecol];
            const float gf = gbuf[1][erow][ecol];
            const float gg = gbuf[2][erow][ecol];
            const float go = gbuf[3][erow][ecol];
            const float iv = sigmf(gi);
            const float fv = sigmf(gf);
            const float gv = tanhf_fast(gg);
            const float ov = sigmf(go);
            cst = fv * cst + iv * gv;
            const float hv = ov * tanhf_fast(cst);
            const u32 word = ((u32)(t + 1) << 16) | (u32)f2bf(hv);
            __hip_atomic_store(hbuf + (size_t)(t & 3) * (NB * HD)
                               + (size_t)en * HD + hcol, word,
                               __ATOMIC_RELAXED, __HIP_MEMORY_SCOPE_AGENT);
            y[((size_t)en * 512 + t) * 512 + hcol] = hv;       // off critical path
        }

        // ---- prefetch x fragments for t+1 (overlaps next step's poll)
        if (t + 1 < TS) {
            const u16* xg = xbg + ((size_t)(n0 + m15) * TS + (t + 1)) * HD + kq * 8;
#pragma unroll
            for (int kc = 0; kc < 16; ++kc)
                xb[kc] = *(const short8*)(xg + kc * 32);
        }
    }
}

extern "C" void kernel_launch(void* const* d_in, const int* in_sizes, int n_in,
                              void* d_out, int out_size, void* d_ws, size_t ws_size,
                              hipStream_t stream) {
    const float* x   = (const float*)d_in[0];
    const float* wxh = (const float*)d_in[1];
    const float* whh = (const float*)d_in[2];
    const float* bxh = (const float*)d_in[3];
    const float* bhh = (const float*)d_in[4];
    float* y = (float*)d_out;

    char* ws = (char*)d_ws;
    u32* hbuf = (u32*)ws;                                     // 512 KB ring (4 slots)
    u16* WtX  = (u16*)(ws + (size_t)(1 << 19));               // 2 MB
    u16* WtH  = (u16*)(ws + (size_t)(1 << 19) + (size_t)2048 * 512 * 2);
    u16* xbg  = (u16*)(ws + (size_t)(1 << 19) + (size_t)2 * 2048 * 512 * 2);  // 32 MB

    // hbuf needs no init: 0xAAAA poison never matches tags 1..512.

    cvt_x_k<<<2048, 256, 0, stream>>>(x, xbg, NB * TS * HD);

    dim3 tgrid(2048 / 32, 512 / 32);
    transpose_cvt_k<<<tgrid, 256, 0, stream>>>(wxh, WtX, 512, 2048);
    transpose_cvt_k<<<tgrid, 256, 0, stream>>>(whh, WtH, 512, 2048);

    lstm_fused<<<dim3(NBLK), dim3(256), 0, stream>>>(xbg, WtX, WtH, bxh, bhh,
                                                     hbuf, y);
}

// Round 6
// 2598.283 us; speedup vs baseline: 1.0535x; 1.0535x over previous
//
#include <hip/hip_runtime.h>

typedef unsigned short u16;
typedef unsigned int   u32;
typedef unsigned long long u64;
typedef __attribute__((ext_vector_type(8))) short short8;   // 8 x bf16 (4 VGPR)
typedef __attribute__((ext_vector_type(4))) float f32x4;
typedef __attribute__((ext_vector_type(4))) u32   u32x4;
typedef __attribute__((ext_vector_type(2))) unsigned long long u64x2;

#define NB   64      // batch
#define TS   512     // timesteps
#define HD   512     // hidden
#define RG   4       // row-chains (16 batch rows each)
#define CG   32      // col-groups (16 h-cols each)
#define LP   520     // ldsH pitch in u16 (1040 B)

__device__ __forceinline__ u16 f2bf(float x) {
    union { float f; u32 i; } v; v.f = x;
    u32 r = (v.i + 0x7fffu + ((v.i >> 16) & 1u)) >> 16;
    return (u16)r;
}
__device__ __forceinline__ u32 pack2bf(float a, float b) {
    return (u32)f2bf(a) | ((u32)f2bf(b) << 16);
}
__device__ __forceinline__ float sigmf(float x) { return 1.0f / (1.0f + __expf(-x)); }
__device__ __forceinline__ float tanhf_fast(float x) { return 1.0f - 2.0f / (__expf(2.0f * x) + 1.0f); }

__device__ __forceinline__ u32 get_xcc() {
    u32 v;
    asm("s_getreg_b32 %0, hwreg(HW_REG_XCC_ID)" : "=s"(v));
    return v & 0xfu;
}
// sc0-only store: lands in this XCD's L2 (coherent intra-XCD, bypasses L1)
__device__ __forceinline__ void st_sc0(u32* p, u32 v) {
    asm volatile("global_store_dword %0, %1, off sc0" :: "v"(p), "v"(v) : "memory");
}
// 16 u64 batched sc0 loads (128 B) + single drain
__device__ __forceinline__ void ld16_sc0(const u64* p, u64* h) {
    asm volatile(
        "global_load_dwordx2 %0, %16, off sc0\n\t"
        "global_load_dwordx2 %1, %16, off offset:8 sc0\n\t"
        "global_load_dwordx2 %2, %16, off offset:16 sc0\n\t"
        "global_load_dwordx2 %3, %16, off offset:24 sc0\n\t"
        "global_load_dwordx2 %4, %16, off offset:32 sc0\n\t"
        "global_load_dwordx2 %5, %16, off offset:40 sc0\n\t"
        "global_load_dwordx2 %6, %16, off offset:48 sc0\n\t"
        "global_load_dwordx2 %7, %16, off offset:56 sc0\n\t"
        "global_load_dwordx2 %8, %16, off offset:64 sc0\n\t"
        "global_load_dwordx2 %9, %16, off offset:72 sc0\n\t"
        "global_load_dwordx2 %10, %16, off offset:80 sc0\n\t"
        "global_load_dwordx2 %11, %16, off offset:88 sc0\n\t"
        "global_load_dwordx2 %12, %16, off offset:96 sc0\n\t"
        "global_load_dwordx2 %13, %16, off offset:104 sc0\n\t"
        "global_load_dwordx2 %14, %16, off offset:112 sc0\n\t"
        "global_load_dwordx2 %15, %16, off offset:120 sc0\n\t"
        "s_waitcnt vmcnt(0)"
        : "=&v"(h[0]), "=&v"(h[1]), "=&v"(h[2]), "=&v"(h[3]),
          "=&v"(h[4]), "=&v"(h[5]), "=&v"(h[6]), "=&v"(h[7]),
          "=&v"(h[8]), "=&v"(h[9]), "=&v"(h[10]), "=&v"(h[11]),
          "=&v"(h[12]), "=&v"(h[13]), "=&v"(h[14]), "=&v"(h[15])
        : "v"(p)
        : "memory");
}

// ---- x: f32 -> bf16, elementwise (one-time) -------------------------------
__global__ void cvt_x_k(const float* __restrict__ in, u16* __restrict__ out, int n) {
    int i = (blockIdx.x * blockDim.x + threadIdx.x) * 8;
    const int stride = gridDim.x * blockDim.x * 8;
    for (; i < n; i += stride) {
        const f32x4 a = *(const f32x4*)(in + i);
        const f32x4 b = *(const f32x4*)(in + i + 4);
        u32 q[4];
        q[0] = pack2bf(a[0], a[1]);
        q[1] = pack2bf(a[2], a[3]);
        q[2] = pack2bf(b[0], b[1]);
        q[3] = pack2bf(b[2], b[3]);
        *(f32x4*)(out + i) = *(f32x4*)q;
    }
}

// ---- transpose + f32->bf16 convert: in (R x C) f32 -> out (C x R) bf16 ----
__global__ void transpose_cvt_k(const float* __restrict__ in, u16* __restrict__ out,
                                int R, int C) {
    __shared__ float tile[32][33];
    const int c0 = blockIdx.x * 32;
    const int r0 = blockIdx.y * 32;
    const int tx = threadIdx.x & 31;
    const int ty = threadIdx.x >> 5;
#pragma unroll
    for (int i = 0; i < 32; i += 8)
        tile[ty + i][tx] = in[(size_t)(r0 + ty + i) * C + c0 + tx];
    __syncthreads();
#pragma unroll
    for (int i = 0; i < 32; i += 8)
        out[(size_t)(c0 + ty + i) * R + r0 + tx] = f2bf(tile[tx][ty + i]);
}

// ---- persistent fused LSTM ------------------------------------------------
// Launch 256 blocks; odd bids exit. Worker bid = 2r + 8cg  ->  chain r,
// col-group cg. Under round-robin bid%8->XCD mapping, chain r sits wholly on
// XCD 2r. Chain members exchange XCC_IDs once (agent scope); if all equal,
// use sc0-only (XCD-L2 coherent) tagged-word transport; else fall back to the
// verified agent-scope flag protocol. Decision is chain-uniform either way.
__global__ __launch_bounds__(256, 1) void lstm_fused(
    const u16*   __restrict__ xbg,   // (64,512,512) bf16
    const u16*   __restrict__ WtX,   // (2048,512) bf16 = W_xh^T
    const u16*   __restrict__ WtH,   // (2048,512) bf16 = W_hh^T
    const float* __restrict__ bxh,   // (2048) f32
    const float* __restrict__ bhh,   // (2048) f32
    u64*   __restrict__ hslow,       // ring: (4, 64, 128) u64 bf16 rows
    u32*   __restrict__ hfast,       // ring: (4, 64, 512) u32 tagged bf16
    float* __restrict__ y,           // (64,512,512) f32
    u32*   __restrict__ flags,       // (512,4,32) one-shot (slow path)
    u32*   __restrict__ xcdtab)      // (128) xcd exchange
{
    const int bid = blockIdx.x;
    if (bid & 1) return;
    const int r    = (bid >> 1) & 3;
    const int cg   = bid >> 3;
    const int tid  = threadIdx.x;
    const int lane = tid & 63;
    const int wv   = tid >> 6;          // gate index 0..3
    const int m15  = lane & 15;
    const int kq   = lane >> 4;
    const int n0   = r * 16;
    const int gcol0 = wv * 512 + cg * 16;
    const int widx  = r * 32 + cg;

    __shared__ u16   ldsH[16 * LP];     // 16.6 KB staged h tile (bf16)
    __shared__ float gbuf[4][16][17];
    __shared__ u16   ht[16][16];        // slow-path publish staging

    // ---- one-time XCD-id exchange (agent scope), chain-uniform decision ----
    const u32 myxcd = get_xcc();
    if (tid == 0)
        __hip_atomic_store(xcdtab + widx, 0xC0DE0000u | myxcd,
                           __ATOMIC_RELAXED, __HIP_MEMORY_SCOPE_AGENT);
    u32 pv;
    do {
        pv = __hip_atomic_load(xcdtab + r * 32 + (lane & 31),
                               __ATOMIC_RELAXED, __HIP_MEMORY_SCOPE_AGENT);
    } while (!__all((pv >> 16) == 0xC0DEu));
    const bool fast = __all((pv & 0xffu) == myxcd);

    // --- preload W fragments (B-operand: n = lane&15, k = kq*8 + j) ---
    short8 wx[16], wh[16];
    {
        const u16* px = WtX + (size_t)(gcol0 + m15) * 512 + kq * 8;
        const u16* ph = WtH + (size_t)(gcol0 + m15) * 512 + kq * 8;
#pragma unroll
        for (int kc = 0; kc < 16; ++kc) {
            wx[kc] = *(const short8*)(px + kc * 32);
            wh[kc] = *(const short8*)(ph + kc * 32);
        }
    }
    const float bsum = bxh[gcol0 + m15] + bhh[gcol0 + m15];

    const int erow = tid >> 4;
    const int ecol = tid & 15;
    const int en   = n0 + erow;
    const int hcol = cg * 16 + ecol;
    float cst = 0.0f;

    // consume assignment: wave wv covers local rows [4wv,4wv+4);
    // lane -> row 4wv+(lane>>4), 32 bf16 cols starting at (lane&15)*32
    const int lrow = 4 * wv + (lane >> 4);

    // ---- seed x fragments for t=0
    short8 xb[16];
    {
        const u16* xg = xbg + ((size_t)(n0 + m15) * TS + 0) * HD + kq * 8;
#pragma unroll
        for (int kc = 0; kc < 16; ++kc)
            xb[kc] = *(const short8*)(xg + kc * 32);
    }

    for (int t = 0; t < TS; ++t) {
        // ---- x-part MFMA (overlaps the h wait)
        f32x4 a0 = {0.f,0.f,0.f,0.f}, a1 = {0.f,0.f,0.f,0.f};
        f32x4 a2 = {0.f,0.f,0.f,0.f}, a3 = {0.f,0.f,0.f,0.f};
#pragma unroll
        for (int kc = 0; kc < 4; ++kc) {
            a0 = __builtin_amdgcn_mfma_f32_16x16x32_bf16(xb[4*kc + 0], wx[4*kc + 0], a0, 0, 0, 0);
            a1 = __builtin_amdgcn_mfma_f32_16x16x32_bf16(xb[4*kc + 1], wx[4*kc + 1], a1, 0, 0, 0);
            a2 = __builtin_amdgcn_mfma_f32_16x16x32_bf16(xb[4*kc + 2], wx[4*kc + 2], a2, 0, 0, 0);
            a3 = __builtin_amdgcn_mfma_f32_16x16x32_bf16(xb[4*kc + 3], wx[4*kc + 3], a3, 0, 0, 0);
        }

        if (t > 0) {
            if (fast) {
                // ---- poll tagged words directly in XCD-local L2 (sc0)
                const u32 tagexp = (u32)t;
                const u64 pat = ((u64)tagexp << 48) | ((u64)tagexp << 16);
                const u64* src = (const u64*)(hfast + (size_t)((t - 1) & 3) * (NB * HD)
                                            + (size_t)(n0 + lrow) * HD + (lane & 15) * 32);
                u64 hq[16];
                bool ok;
                do {
                    ld16_sc0(src, hq);
                    ok = true;
#pragma unroll
                    for (int i = 0; i < 16; ++i)
                        ok = ok && ((hq[i] & 0xFFFF0000FFFF0000ULL) == pat);
                } while (!__all(ok));
                // strip tags, pack 32 bf16, share via LDS
                u32 pk[16];
#pragma unroll
                for (int i = 0; i < 16; ++i) {
                    const u32 lo = (u32)hq[i];
                    const u32 hi = (u32)(hq[i] >> 32);
                    pk[i] = (lo & 0xFFFFu) | (hi << 16);
                }
                u32* ldst = (u32*)(ldsH + lrow * LP + (lane & 15) * 32);
                *(u32x4*)(ldst)      = *(u32x4*)(pk);
                *(u32x4*)(ldst + 4)  = *(u32x4*)(pk + 4);
                *(u32x4*)(ldst + 8)  = *(u32x4*)(pk + 8);
                *(u32x4*)(ldst + 12) = *(u32x4*)(pk + 12);
            } else {
                // ---- slow path: agent flags + one-shot quarter loads (R4)
                const u32* fl = flags + (size_t)(t - 1) * (RG * CG) + r * CG;
                u32 v;
                do {
                    v = __hip_atomic_load(fl + (lane & 31), __ATOMIC_RELAXED,
                                          __HIP_MEMORY_SCOPE_AGENT);
                } while (!__all(v != 0u));
                const u64* gsrc = hslow + (size_t)((t - 1) & 3) * (NB * 128)
                                + (size_t)(n0 + lrow) * 128 + (lane & 15) * 8;
                u64 hq8[8];
#pragma unroll
                for (int i = 0; i < 8; ++i)
                    hq8[i] = __hip_atomic_load(gsrc + i, __ATOMIC_RELAXED,
                                               __HIP_MEMORY_SCOPE_AGENT);
                u64* ldst = ((u64*)(ldsH + lrow * LP)) + (lane & 15) * 8;
                *(u64x2*)(ldst)     = (u64x2){hq8[0], hq8[1]};
                *(u64x2*)(ldst + 2) = (u64x2){hq8[2], hq8[3]};
                *(u64x2*)(ldst + 4) = (u64x2){hq8[4], hq8[5]};
                *(u64x2*)(ldst + 6) = (u64x2){hq8[6], hq8[7]};
            }
            __syncthreads();                                   // B1

            // ---- h-part MFMA from LDS A-frags
            const u16* lh = ldsH + m15 * LP + kq * 8;
#pragma unroll
            for (int kc = 0; kc < 4; ++kc) {
                short8 h0 = *(const short8*)(lh + (4*kc + 0) * 32);
                short8 h1 = *(const short8*)(lh + (4*kc + 1) * 32);
                short8 h2 = *(const short8*)(lh + (4*kc + 2) * 32);
                short8 h3 = *(const short8*)(lh + (4*kc + 3) * 32);
                a0 = __builtin_amdgcn_mfma_f32_16x16x32_bf16(h0, wh[4*kc + 0], a0, 0, 0, 0);
                a1 = __builtin_amdgcn_mfma_f32_16x16x32_bf16(h1, wh[4*kc + 1], a1, 0, 0, 0);
                a2 = __builtin_amdgcn_mfma_f32_16x16x32_bf16(h2, wh[4*kc + 2], a2, 0, 0, 0);
                a3 = __builtin_amdgcn_mfma_f32_16x16x32_bf16(h3, wh[4*kc + 3], a3, 0, 0, 0);
            }
        }

        // ---- merge gates into LDS (C/D layout: col = lane&15, row = kq*4+reg)
        {
            f32x4 g4 = a0 + a1 + a2 + a3;
#pragma unroll
            for (int j = 0; j < 4; ++j)
                gbuf[wv][kq * 4 + j][m15] = g4[j] + bsum;
        }
        __syncthreads();                                       // B2

        // ---- elementwise LSTM cell + publish
        {
            const float gi = gbuf[0][erow][ecol];
            const float gf = gbuf[1][erow][ecol];
            const float gg = gbuf[2][erow][ecol];
            const float go = gbuf[3][erow][ecol];
            const float iv = sigmf(gi);
            const float fv = sigmf(gf);
            const float gv = tanhf_fast(gg);
            const float ov = sigmf(go);
            cst = fv * cst + iv * gv;
            const float hv = ov * tanhf_fast(cst);
            const u16 hb = f2bf(hv);
            if (fast) {
                // tagged word straight into XCD-local L2; tag atomic with data.
                // B2 of next step drains vmcnt -> same-address order across ring reuse.
                st_sc0(hfast + (size_t)(t & 3) * (NB * HD) + (size_t)en * HD + hcol,
                       ((u32)(t + 1) << 16) | (u32)hb);
            } else {
                ht[erow][ecol] = hb;
            }
            y[((size_t)en * 512 + t) * 512 + hcol] = hv;       // off critical path
        }

        if (!fast) {
            __syncthreads();                                   // B3 (slow only)
            if (tid < 64) {
                const int row = tid >> 2;
                const int c4  = tid & 3;
                const u64 v = *(const u64*)&ht[row][c4 * 4];
                __hip_atomic_store(hslow + (size_t)(t & 3) * (NB * 128)
                                   + (size_t)(n0 + row) * 128 + cg * 4 + c4, v,
                                   __ATOMIC_RELAXED, __HIP_MEMORY_SCOPE_AGENT);
            }
            __syncthreads();                                   // B4: drain stores
            if (t < TS - 1 && tid == 0)
                __hip_atomic_store(flags + (size_t)t * (RG * CG) + r * CG + cg, 1u,
                                   __ATOMIC_RELAXED, __HIP_MEMORY_SCOPE_AGENT);
        }

        // ---- prefetch x fragments for t+1
        if (t + 1 < TS) {
            const u16* xg = xbg + ((size_t)(n0 + m15) * TS + (t + 1)) * HD + kq * 8;
#pragma unroll
            for (int kc = 0; kc < 16; ++kc)
                xb[kc] = *(const short8*)(xg + kc * 32);
        }
    }
}

extern "C" void kernel_launch(void* const* d_in, const int* in_sizes, int n_in,
                              void* d_out, int out_size, void* d_ws, size_t ws_size,
                              hipStream_t stream) {
    const float* x   = (const float*)d_in[0];
    const float* wxh = (const float*)d_in[1];
    const float* whh = (const float*)d_in[2];
    const float* bxh = (const float*)d_in[3];
    const float* bhh = (const float*)d_in[4];
    float* y = (float*)d_out;

    char* ws = (char*)d_ws;
    u32* flags  = (u32*)ws;                                   // 256 KB @ 0
    u64* hslow  = (u64*)(ws + (size_t)(1 << 18));             // 256 KB
    u32* hfast  = (u32*)(ws + (size_t)(2 << 18));             // 512 KB
    u32* xcdtab = (u32*)(ws + (size_t)(4 << 18));             // 512 B
    u16* WtX    = (u16*)(ws + (size_t)(4 << 18) + 4096);      // 2 MB
    u16* WtH    = (u16*)(ws + (size_t)(4 << 18) + 4096 + (size_t)2048 * 512 * 2);
    u16* xbg    = (u16*)(ws + (size_t)(4 << 18) + 4096 + (size_t)2 * 2048 * 512 * 2);

    (void)hipMemsetAsync(flags, 0, (size_t)TS * RG * CG * sizeof(u32), stream);
    // xcdtab/hfast need no init: 0xAA poison never matches 0xC0DE / tags 1..512.

    cvt_x_k<<<2048, 256, 0, stream>>>(x, xbg, NB * TS * HD);

    dim3 tgrid(2048 / 32, 512 / 32);
    transpose_cvt_k<<<tgrid, 256, 0, stream>>>(wxh, WtX, 512, 2048);
    transpose_cvt_k<<<tgrid, 256, 0, stream>>>(whh, WtH, 512, 2048);

    lstm_fused<<<dim3(256), dim3(256), 0, stream>>>(xbg, WtX, WtH, bxh, bhh,
                                                    hslow, hfast, y, flags, xcdtab);
}